// Round 1
// baseline (664.420 us; speedup 1.0000x reference)
//
#include <hip/hip_runtime.h>
#include <hip/hip_bf16.h>
#include <stdint.h>

using bf16 = __hip_bfloat16;
typedef __attribute__((ext_vector_type(8))) short short8;
typedef __attribute__((ext_vector_type(4))) float floatx4;

#define DEVINL __device__ __forceinline__

constexpr int K_DIM = 4096;
constexpr int N_DIM = 4096;
constexpr int M_DIM = 8192;   // B * S = 2 * 4096

constexpr int BM = 128, BN = 128, BK = 32;
constexpr int NBLK_N = N_DIM / BN;   // 32

// ---- async global->LDS, 16B per lane; LDS dest = wave-uniform base + lane*16
DEVINL void gload_lds16(const void* g, void* l) {
  __builtin_amdgcn_global_load_lds((const __attribute__((address_space(1))) void*)g,
                                   (__attribute__((address_space(3))) void*)l,
                                   16, 0, 0);
}

// --- Kernel 1: A fp32 -> bf16, 8 elements / thread
__global__ __launch_bounds__(256) void k_a_convert(const float* __restrict__ a,
                                                   bf16* __restrict__ o) {
  int t = blockIdx.x * 256 + threadIdx.x;
  const float4* a4 = (const float4*)a;
  float4 v0 = a4[2 * t], v1 = a4[2 * t + 1];
  bf16 h[8];
  h[0] = __float2bfloat16(v0.x); h[1] = __float2bfloat16(v0.y);
  h[2] = __float2bfloat16(v0.z); h[3] = __float2bfloat16(v0.w);
  h[4] = __float2bfloat16(v1.x); h[5] = __float2bfloat16(v1.y);
  h[6] = __float2bfloat16(v1.z); h[7] = __float2bfloat16(v1.w);
  ((uint4*)o)[t] = *(const uint4*)h;
}

// --- Kernel 2: GPTQ int4 dequant -> bf16 W^T stored [N][K]
// w[k][n] = ((qw[k/8][n] >> 4*(k%8)) & 0xF - z[g][n]) * s[g][n], g = k/128
// One thread per packed int32 (8 consecutive k for one n) -> one contiguous
// 16B store in the [N][K] layout.
__global__ __launch_bounds__(256) void k_dequant(const int* __restrict__ qw,
                                                 const float* __restrict__ scales,
                                                 const int* __restrict__ qz,
                                                 bf16* __restrict__ wt) {
  int t = blockIdx.x * 256 + threadIdx.x;   // [0, N * K/8)
  int kp = t & (K_DIM / 8 - 1);             // 0..511
  int n  = t >> 9;
  int q = qw[kp * N_DIM + n];
  int g = kp >> 4;                          // (kp*8)/128
  float s = scales[g * N_DIM + n];
  int zword = qz[g * (N_DIM / 8) + (n >> 3)];
  float z = (float)((zword >> ((n & 7) * 4)) & 0xF);
  float nzs = -z * s;
  bf16 h[8];
#pragma unroll
  for (int i = 0; i < 8; ++i) {
    float w = fmaf((float)((q >> (4 * i)) & 0xF), s, nzs);
    h[i] = __float2bfloat16(w);
  }
  ((uint4*)wt)[n * (K_DIM / 8) + kp] = *(const uint4*)h;
}

// --- Kernel 3: bf16 MFMA GEMM (m97 structure) + fused bias/residual epilogue
// A: [M][K] (bf16 if A_IS_BF16 else fp32), Wt: [N][K] bf16, out fp32 [M][N]
template <bool A_IS_BF16>
__global__ __launch_bounds__(256, 2) void k_gemm(const void* __restrict__ a_ptr,
                                                 const bf16* __restrict__ wt,
                                                 const float* __restrict__ bias,
                                                 const float* __restrict__ residual,
                                                 float* __restrict__ out) {
  __shared__ __align__(16) bf16 As[BM * BK];  // [m][k], 8 KB
  __shared__ __align__(16) bf16 Bs[BN * BK];  // [n][k], 8 KB

  const int tid  = threadIdx.x;
  const int lane = tid & 63;
  const int wave = tid >> 6;
  const int wr = wave >> 1, wc = wave & 1;   // 2x2 waves, 64x64 each
  const int quad = lane >> 4, lq = lane & 15;

  const int bid = blockIdx.x;
  const int bm = bid / NBLK_N, bn = bid % NBLK_N;
  const int m0 = bm * BM, n0 = bn * BN;

  floatx4 acc[4][4] = {};

  // staging: 8 chunks of 16 rows x 32 cols; wave w does chunks {w, w+4};
  // within a chunk lane i covers row i/4, 8 elements at col (i%4)*8
  const int st_row = lane >> 2;
  const int st_c8  = (lane & 3) * 8;

  const bf16*  a_bf = (const bf16*)a_ptr;
  const float* a_f  = (const float*)a_ptr;

  for (int k0 = 0; k0 < K_DIM; k0 += BK) {
    __syncthreads();
#pragma unroll
    for (int j = 0; j < 2; ++j) {
      int q = wave + j * 4;
      const bf16* g = wt + (size_t)(n0 + q * 16 + st_row) * K_DIM + k0 + st_c8;
      gload_lds16(g, &Bs[q * 512]);
    }
    if (A_IS_BF16) {
#pragma unroll
      for (int j = 0; j < 2; ++j) {
        int q = wave + j * 4;
        const bf16* g = a_bf + (size_t)(m0 + q * 16 + st_row) * K_DIM + k0 + st_c8;
        gload_lds16(g, &As[q * 512]);
      }
    } else {
      // fp32 fallback staging: thread t -> row t/2, 16 floats at col (t&1)*16
      int row = tid >> 1, cb = (tid & 1) * 16;
      const float* srcf = a_f + (size_t)(m0 + row) * K_DIM + k0 + cb;
      float4 v0 = ((const float4*)srcf)[0];
      float4 v1 = ((const float4*)srcf)[1];
      float4 v2 = ((const float4*)srcf)[2];
      float4 v3 = ((const float4*)srcf)[3];
      bf16 h[16];
      h[0]  = __float2bfloat16(v0.x); h[1]  = __float2bfloat16(v0.y);
      h[2]  = __float2bfloat16(v0.z); h[3]  = __float2bfloat16(v0.w);
      h[4]  = __float2bfloat16(v1.x); h[5]  = __float2bfloat16(v1.y);
      h[6]  = __float2bfloat16(v1.z); h[7]  = __float2bfloat16(v1.w);
      h[8]  = __float2bfloat16(v2.x); h[9]  = __float2bfloat16(v2.y);
      h[10] = __float2bfloat16(v2.z); h[11] = __float2bfloat16(v2.w);
      h[12] = __float2bfloat16(v3.x); h[13] = __float2bfloat16(v3.y);
      h[14] = __float2bfloat16(v3.z); h[15] = __float2bfloat16(v3.w);
      *(uint4*)&As[row * BK + cb]     = *(const uint4*)h;
      *(uint4*)&As[row * BK + cb + 8] = *(const uint4*)(h + 8);
    }
    __syncthreads();

    short8 afr[4], bfr[4];
#pragma unroll
    for (int mi = 0; mi < 4; ++mi)
      afr[mi] = *(const short8*)&As[(wr * 64 + mi * 16 + lq) * BK + quad * 8];
#pragma unroll
    for (int ni = 0; ni < 4; ++ni)
      bfr[ni] = *(const short8*)&Bs[(wc * 64 + ni * 16 + lq) * BK + quad * 8];
#pragma unroll
    for (int mi = 0; mi < 4; ++mi)
#pragma unroll
      for (int ni = 0; ni < 4; ++ni)
        acc[mi][ni] = __builtin_amdgcn_mfma_f32_16x16x32_bf16(afr[mi], bfr[ni],
                                                              acc[mi][ni], 0, 0, 0);
  }

  // epilogue: out = acc + bias + residual; C/D layout col=lane&15, row=quad*4+r
#pragma unroll
  for (int ni = 0; ni < 4; ++ni) {
    int col = n0 + wc * 64 + ni * 16 + lq;
    float bv = bias[col];
#pragma unroll
    for (int mi = 0; mi < 4; ++mi) {
      int rbase = m0 + wr * 64 + mi * 16 + quad * 4;
#pragma unroll
      for (int r = 0; r < 4; ++r) {
        size_t idx = (size_t)(rbase + r) * N_DIM + col;
        out[idx] = acc[mi][ni][r] + bv + residual[idx];
      }
    }
  }
}

extern "C" void kernel_launch(void* const* d_in, const int* in_sizes, int n_in,
                              void* d_out, int out_size, void* d_ws, size_t ws_size,
                              hipStream_t stream) {
  const float* input    = (const float*)d_in[0];
  const float* residual = (const float*)d_in[1];
  const int*   qweight  = (const int*)d_in[2];
  const float* scales   = (const float*)d_in[3];
  const int*   qzeros   = (const int*)d_in[4];
  const float* bias     = (const float*)d_in[5];
  float* out = (float*)d_out;

  const size_t wt_bytes = (size_t)N_DIM * K_DIM * sizeof(bf16);   // 32 MiB
  const size_t a_bytes  = (size_t)M_DIM * K_DIM * sizeof(bf16);   // 64 MiB

  bf16* wt = (bf16*)d_ws;
  k_dequant<<<(N_DIM * (K_DIM / 8)) / 256, 256, 0, stream>>>(qweight, scales, qzeros, wt);

  if (ws_size >= wt_bytes + a_bytes) {
    bf16* a_bf = (bf16*)((char*)d_ws + wt_bytes);
    k_a_convert<<<(M_DIM * K_DIM / 8) / 256, 256, 0, stream>>>(input, a_bf);
    k_gemm<true><<<(M_DIM / BM) * (N_DIM / BN), 256, 0, stream>>>(a_bf, wt, bias, residual, out);
  } else {
    k_gemm<false><<<(M_DIM / BM) * (N_DIM / BN), 256, 0, stream>>>(input, wt, bias, residual, out);
  }
}

// Round 2
// 648.598 us; speedup vs baseline: 1.0244x; 1.0244x over previous
//
#include <hip/hip_runtime.h>
#include <hip/hip_bf16.h>
#include <stdint.h>

using bf16 = __hip_bfloat16;
typedef __attribute__((ext_vector_type(8))) short short8;
typedef __attribute__((ext_vector_type(4))) float floatx4;

#define DEVINL __device__ __forceinline__

constexpr int K_DIM = 4096;
constexpr int N_DIM = 4096;
constexpr int M_DIM = 8192;   // B * S = 2 * 4096

constexpr int BM = 128, BN = 128, BK = 32;
constexpr int NBLK_N = N_DIM / BN;   // 32

// ---- async global->LDS, 16B per lane; LDS dest = wave-uniform base + lane*16
DEVINL void gload_lds16(const void* g, void* l) {
  __builtin_amdgcn_global_load_lds((const __attribute__((address_space(1))) void*)g,
                                   (__attribute__((address_space(3))) void*)l,
                                   16, 0, 0);
}

// --- Kernel 1: A fp32 -> bf16, 8 elements / thread
__global__ __launch_bounds__(256) void k_a_convert(const float* __restrict__ a,
                                                   bf16* __restrict__ o) {
  int t = blockIdx.x * 256 + threadIdx.x;
  const float4* a4 = (const float4*)a;
  float4 v0 = a4[2 * t], v1 = a4[2 * t + 1];
  bf16 h[8];
  h[0] = __float2bfloat16(v0.x); h[1] = __float2bfloat16(v0.y);
  h[2] = __float2bfloat16(v0.z); h[3] = __float2bfloat16(v0.w);
  h[4] = __float2bfloat16(v1.x); h[5] = __float2bfloat16(v1.y);
  h[6] = __float2bfloat16(v1.z); h[7] = __float2bfloat16(v1.w);
  ((uint4*)o)[t] = *(const uint4*)h;
}

// --- Kernel 2: GPTQ int4 dequant -> bf16 W^T stored [N][K]
// Coalesced read (n fastest across lanes), LDS transpose, 128B-run writes.
// Tile: 8 packed-k rows x 32 n cols; 256 threads, 1 packed word each.
__global__ __launch_bounds__(256) void k_dequant(const int* __restrict__ qw,
                                                 const float* __restrict__ scales,
                                                 const int* __restrict__ qz,
                                                 bf16* __restrict__ wt) {
  __shared__ __align__(16) uint4 lds[32 * 8];   // [n_local][kp_local^swz], 4 KB
  const int b = blockIdx.x;
  const int kp0 = (b & 63) * 8;                 // 512/8 = 64 kp-tiles
  const int n0  = (b >> 6) * 32;                // 4096/32 = 128 n-tiles
  const int t = threadIdx.x;
  const int n_l = t & 31, kp_l = t >> 5;
  const int n = n0 + n_l, kp = kp0 + kp_l;

  int q = qw[kp * N_DIM + n];                   // lanes: n consecutive -> coalesced
  int g = kp0 >> 4;                             // uniform over tile (kp0 % 8 == 0)
  float s = scales[g * N_DIM + n];
  int zword = qz[g * (N_DIM / 8) + (n >> 3)];
  float z = (float)((zword >> ((n & 7) * 4)) & 0xF);
  float nzs = -z * s;
  bf16 h[8];
#pragma unroll
  for (int i = 0; i < 8; ++i) {
    float w = fmaf((float)((q >> (4 * i)) & 0xF), s, nzs);
    h[i] = __float2bfloat16(w);
  }
  lds[n_l * 8 + (kp_l ^ (n_l & 7))] = *(const uint4*)h;
  __syncthreads();
  const int n_o = t >> 3, kp_o = t & 7;
  uint4 v = lds[n_o * 8 + (kp_o ^ (n_o & 7))];
  ((uint4*)wt)[(size_t)(n0 + n_o) * (K_DIM / 8) + kp0 + kp_o] = v;
}

// --- Kernel 3: bf16 MFMA GEMM (m97 structure) + fused bias/residual epilogue
// LDS tiles XOR-swizzled: logical 16B chunk c of row r lives at physical
// chunk c ^ ((r>>1)&3)  ->  fragment ds_read_b128 is 2-way (free) instead of 8-way.
template <bool A_IS_BF16>
__global__ __launch_bounds__(256, 2) void k_gemm(const void* __restrict__ a_ptr,
                                                 const bf16* __restrict__ wt,
                                                 const float* __restrict__ bias,
                                                 const float* __restrict__ residual,
                                                 float* __restrict__ out) {
  __shared__ __align__(16) bf16 As[BM * BK];  // 8 KB
  __shared__ __align__(16) bf16 Bs[BN * BK];  // 8 KB

  const int tid  = threadIdx.x;
  const int lane = tid & 63;
  const int wave = tid >> 6;
  const int wr = wave >> 1, wc = wave & 1;   // 2x2 waves, 64x64 each
  const int quad = lane >> 4, lq = lane & 15;
  const int sw = (lane >> 1) & 3;            // read-side swizzle ((lq>>1)&3)
  const int rd_c8 = (quad ^ sw) * 8;         // physical chunk for logical quad

  const int bid = blockIdx.x;
  const int bm = bid / NBLK_N, bn = bid % NBLK_N;
  const int m0 = bm * BM, n0 = bn * BN;

  floatx4 acc[4][4] = {};

  // staging: chunk row = lane>>2; lane's logical chunk = (lane&3) ^ ((lane>>3)&3)
  const int st_row = lane >> 2;
  const int st_c8  = ((lane & 3) ^ ((lane >> 3) & 3)) * 8;

  const bf16*  a_bf = (const bf16*)a_ptr;
  const float* a_f  = (const float*)a_ptr;

  for (int k0 = 0; k0 < K_DIM; k0 += BK) {
    __syncthreads();
#pragma unroll
    for (int j = 0; j < 2; ++j) {
      int q = wave + j * 4;
      const bf16* g = wt + (size_t)(n0 + q * 16 + st_row) * K_DIM + k0 + st_c8;
      gload_lds16(g, &Bs[q * 512]);
    }
    if (A_IS_BF16) {
#pragma unroll
      for (int j = 0; j < 2; ++j) {
        int q = wave + j * 4;
        const bf16* g = a_bf + (size_t)(m0 + q * 16 + st_row) * K_DIM + k0 + st_c8;
        gload_lds16(g, &As[q * 512]);
      }
    } else {
      // fp32 fallback staging: thread t -> row t/2, 16 floats at col (t&1)*16
      int row = tid >> 1, c0 = (tid & 1) * 2;  // two 16B chunks c0, c0+1
      int rsw = (row >> 1) & 3;
      const float* srcf = a_f + (size_t)(m0 + row) * K_DIM + k0 + c0 * 8;
      float4 v0 = ((const float4*)srcf)[0];
      float4 v1 = ((const float4*)srcf)[1];
      float4 v2 = ((const float4*)srcf)[2];
      float4 v3 = ((const float4*)srcf)[3];
      bf16 h[16];
      h[0]  = __float2bfloat16(v0.x); h[1]  = __float2bfloat16(v0.y);
      h[2]  = __float2bfloat16(v0.z); h[3]  = __float2bfloat16(v0.w);
      h[4]  = __float2bfloat16(v1.x); h[5]  = __float2bfloat16(v1.y);
      h[6]  = __float2bfloat16(v1.z); h[7]  = __float2bfloat16(v1.w);
      h[8]  = __float2bfloat16(v2.x); h[9]  = __float2bfloat16(v2.y);
      h[10] = __float2bfloat16(v2.z); h[11] = __float2bfloat16(v2.w);
      h[12] = __float2bfloat16(v3.x); h[13] = __float2bfloat16(v3.y);
      h[14] = __float2bfloat16(v3.z); h[15] = __float2bfloat16(v3.w);
      *(uint4*)&As[row * BK + ((c0 ^ rsw) * 8)]       = *(const uint4*)h;
      *(uint4*)&As[row * BK + (((c0 + 1) ^ rsw) * 8)] = *(const uint4*)(h + 8);
    }
    __syncthreads();

    short8 afr[4], bfr[4];
#pragma unroll
    for (int mi = 0; mi < 4; ++mi)
      afr[mi] = *(const short8*)&As[(wr * 64 + mi * 16 + lq) * BK + rd_c8];
#pragma unroll
    for (int ni = 0; ni < 4; ++ni)
      bfr[ni] = *(const short8*)&Bs[(wc * 64 + ni * 16 + lq) * BK + rd_c8];
#pragma unroll
    for (int mi = 0; mi < 4; ++mi)
#pragma unroll
      for (int ni = 0; ni < 4; ++ni)
        acc[mi][ni] = __builtin_amdgcn_mfma_f32_16x16x32_bf16(afr[mi], bfr[ni],
                                                              acc[mi][ni], 0, 0, 0);
  }

  // epilogue: out = acc + bias + residual; C/D layout col=lane&15, row=quad*4+r
#pragma unroll
  for (int ni = 0; ni < 4; ++ni) {
    int col = n0 + wc * 64 + ni * 16 + lq;
    float bv = bias[col];
#pragma unroll
    for (int mi = 0; mi < 4; ++mi) {
      int rbase = m0 + wr * 64 + mi * 16 + quad * 4;
#pragma unroll
      for (int r = 0; r < 4; ++r) {
        size_t idx = (size_t)(rbase + r) * N_DIM + col;
        out[idx] = acc[mi][ni][r] + bv + residual[idx];
      }
    }
  }
}

extern "C" void kernel_launch(void* const* d_in, const int* in_sizes, int n_in,
                              void* d_out, int out_size, void* d_ws, size_t ws_size,
                              hipStream_t stream) {
  const float* input    = (const float*)d_in[0];
  const float* residual = (const float*)d_in[1];
  const int*   qweight  = (const int*)d_in[2];
  const float* scales   = (const float*)d_in[3];
  const int*   qzeros   = (const int*)d_in[4];
  const float* bias     = (const float*)d_in[5];
  float* out = (float*)d_out;

  const size_t wt_bytes = (size_t)N_DIM * K_DIM * sizeof(bf16);   // 32 MiB
  const size_t a_bytes  = (size_t)M_DIM * K_DIM * sizeof(bf16);   // 64 MiB

  bf16* wt = (bf16*)d_ws;
  k_dequant<<<64 * 128, 256, 0, stream>>>(qweight, scales, qzeros, wt);

  if (ws_size >= wt_bytes + a_bytes) {
    bf16* a_bf = (bf16*)((char*)d_ws + wt_bytes);
    k_a_convert<<<(M_DIM * K_DIM / 8) / 256, 256, 0, stream>>>(input, a_bf);
    k_gemm<true><<<(M_DIM / BM) * (N_DIM / BN), 256, 0, stream>>>(a_bf, wt, bias, residual, out);
  } else {
    k_gemm<false><<<(M_DIM / BM) * (N_DIM / BN), 256, 0, stream>>>(input, wt, bias, residual, out);
  }
}

// Round 3
// 594.758 us; speedup vs baseline: 1.1171x; 1.0905x over previous
//
#include <hip/hip_runtime.h>
#include <hip/hip_bf16.h>
#include <stdint.h>

using bf16 = __hip_bfloat16;
typedef __attribute__((ext_vector_type(8))) short short8;
typedef __attribute__((ext_vector_type(4))) float floatx4;

#define DEVINL __device__ __forceinline__

constexpr int K_DIM = 4096;
constexpr int N_DIM = 4096;
constexpr int M_DIM = 8192;   // B * S = 2 * 4096

constexpr int BM = 128, BN = 128, BK = 64;
constexpr int NBLK_N = N_DIM / BN;   // 32
constexpr int NBLK_M = M_DIM / BM;   // 64

// ---- async global->LDS, 16B per lane; LDS dest = wave-uniform base + lane*16
DEVINL void gload_lds16(const void* g, void* l) {
  __builtin_amdgcn_global_load_lds((const __attribute__((address_space(1))) void*)g,
                                   (__attribute__((address_space(3))) void*)l,
                                   16, 0, 0);
}

// --- Kernel 1: A fp32 -> bf16, 8 elements / thread
__global__ __launch_bounds__(256) void k_a_convert(const float* __restrict__ a,
                                                   bf16* __restrict__ o) {
  int t = blockIdx.x * 256 + threadIdx.x;
  const float4* a4 = (const float4*)a;
  float4 v0 = a4[2 * t], v1 = a4[2 * t + 1];
  bf16 h[8];
  h[0] = __float2bfloat16(v0.x); h[1] = __float2bfloat16(v0.y);
  h[2] = __float2bfloat16(v0.z); h[3] = __float2bfloat16(v0.w);
  h[4] = __float2bfloat16(v1.x); h[5] = __float2bfloat16(v1.y);
  h[6] = __float2bfloat16(v1.z); h[7] = __float2bfloat16(v1.w);
  ((uint4*)o)[t] = *(const uint4*)h;
}

// --- Kernel 2: GPTQ int4 dequant -> bf16 W^T stored [N][K]
// Coalesced read (n fastest across lanes), LDS transpose, 128B-run writes.
__global__ __launch_bounds__(256) void k_dequant(const int* __restrict__ qw,
                                                 const float* __restrict__ scales,
                                                 const int* __restrict__ qz,
                                                 bf16* __restrict__ wt) {
  __shared__ __align__(16) uint4 lds[32 * 8];   // [n_local][kp_local^swz], 4 KB
  const int b = blockIdx.x;
  const int kp0 = (b & 63) * 8;                 // 512/8 = 64 kp-tiles
  const int n0  = (b >> 6) * 32;                // 4096/32 = 128 n-tiles
  const int t = threadIdx.x;
  const int n_l = t & 31, kp_l = t >> 5;
  const int n = n0 + n_l, kp = kp0 + kp_l;

  int q = qw[kp * N_DIM + n];                   // lanes: n consecutive -> coalesced
  int g = kp0 >> 4;                             // uniform over tile (kp0 % 8 == 0)
  float s = scales[g * N_DIM + n];
  int zword = qz[g * (N_DIM / 8) + (n >> 3)];
  float z = (float)((zword >> ((n & 7) * 4)) & 0xF);
  float nzs = -z * s;
  bf16 h[8];
#pragma unroll
  for (int i = 0; i < 8; ++i) {
    float w = fmaf((float)((q >> (4 * i)) & 0xF), s, nzs);
    h[i] = __float2bfloat16(w);
  }
  lds[n_l * 8 + (kp_l ^ (n_l & 7))] = *(const uint4*)h;
  __syncthreads();
  const int n_o = t >> 3, kp_o = t & 7;
  uint4 v = lds[n_o * 8 + (kp_o ^ (n_o & 7))];
  ((uint4*)wt)[(size_t)(n0 + n_o) * (K_DIM / 8) + kp0 + kp_o] = v;
}

// --- Kernel 3: bf16 MFMA GEMM, BK=64 (32 MFMA per barrier pair)
// LDS rows are 128 B = 8 x 16B chunks; logical chunk c of row r lives at
// physical chunk c ^ (r & 7)  -> staging, ds_write and fragment reads all
// hit the 32-bank floor (no conflicts).
// Block swizzle: xcd = bid & 7 owns bn in [xcd*4, xcd*4+4) -> that XCD's L2
// holds a 4 MB wt panel; 4 consecutive idx share one A-tile.
template <bool A_IS_BF16>
__global__ __launch_bounds__(256, 2) void k_gemm(const void* __restrict__ a_ptr,
                                                 const bf16* __restrict__ wt,
                                                 const float* __restrict__ bias,
                                                 const float* __restrict__ residual,
                                                 float* __restrict__ out) {
  __shared__ __align__(16) bf16 As[BM * BK];  // 16 KB
  __shared__ __align__(16) bf16 Bs[BN * BK];  // 16 KB

  const int tid  = threadIdx.x;
  const int lane = tid & 63;
  const int wave = tid >> 6;
  const int wr = wave >> 1, wc = wave & 1;   // 2x2 waves, 64x64 each
  const int quad = lane >> 4, lq = lane & 15;

  const int xcd = blockIdx.x & 7;
  const int idx = blockIdx.x >> 3;           // 0..255
  const int bn = xcd * 4 + (idx & 3);
  const int bm = idx >> 2;
  const int m0 = bm * BM, n0 = bn * BN;

  floatx4 acc[4][4] = {};

  // staging: one instr covers 8 rows x 128 B; lane -> row lane>>3,
  // physical chunk lane&7, so fetch global logical chunk (lane&7)^((lane>>3)&7)
  const int st_r8 = lane >> 3;
  const int st_ce = ((lane & 7) ^ (st_r8 & 7)) * 8;   // element offset in row

  // fragment read: logical chunk (s*4+quad) at row (...|lq) -> phys ^= (lq&7)
  const int rd_x = lq & 7;

  const bf16*  a_bf = (const bf16*)a_ptr;
  const float* a_f  = (const float*)a_ptr;

  for (int k0 = 0; k0 < K_DIM; k0 += BK) {
    __syncthreads();
#pragma unroll
    for (int j = 0; j < 4; ++j) {
      int g = wave + j * 4;                     // row-group 0..15
      const bf16* gp = wt + (size_t)(n0 + g * 8 + st_r8) * K_DIM + k0 + st_ce;
      gload_lds16(gp, &Bs[g * 512]);
    }
    if (A_IS_BF16) {
#pragma unroll
      for (int j = 0; j < 4; ++j) {
        int g = wave + j * 4;
        const bf16* gp = a_bf + (size_t)(m0 + g * 8 + st_r8) * K_DIM + k0 + st_ce;
        gload_lds16(gp, &As[g * 512]);
      }
    } else {
      // fp32 fallback: thread t -> row t>>1, logical chunks [half*4, half*4+4)
      int row = tid >> 1, half = tid & 1;
      int rx = row & 7;
      const float* srcf = a_f + (size_t)(m0 + row) * K_DIM + k0 + half * 32;
#pragma unroll
      for (int cc = 0; cc < 4; ++cc) {
        int logc = half * 4 + cc;
        float4 v0 = ((const float4*)srcf)[cc * 2];
        float4 v1 = ((const float4*)srcf)[cc * 2 + 1];
        bf16 h[8];
        h[0] = __float2bfloat16(v0.x); h[1] = __float2bfloat16(v0.y);
        h[2] = __float2bfloat16(v0.z); h[3] = __float2bfloat16(v0.w);
        h[4] = __float2bfloat16(v1.x); h[5] = __float2bfloat16(v1.y);
        h[6] = __float2bfloat16(v1.z); h[7] = __float2bfloat16(v1.w);
        *(uint4*)&As[row * BK + ((logc ^ rx) * 8)] = *(const uint4*)h;
      }
    }
    __syncthreads();

#pragma unroll
    for (int s = 0; s < 2; ++s) {
      short8 afr[4], bfr[4];
#pragma unroll
      for (int mi = 0; mi < 4; ++mi)
        afr[mi] = *(const short8*)&As[(wr * 64 + mi * 16 + lq) * BK +
                                      (((s * 4 + quad) ^ rd_x) * 8)];
#pragma unroll
      for (int ni = 0; ni < 4; ++ni)
        bfr[ni] = *(const short8*)&Bs[(wc * 64 + ni * 16 + lq) * BK +
                                      (((s * 4 + quad) ^ rd_x) * 8)];
#pragma unroll
      for (int mi = 0; mi < 4; ++mi)
#pragma unroll
        for (int ni = 0; ni < 4; ++ni)
          acc[mi][ni] = __builtin_amdgcn_mfma_f32_16x16x32_bf16(afr[mi], bfr[ni],
                                                                acc[mi][ni], 0, 0, 0);
    }
  }

  // epilogue: out = acc + bias + residual; C/D layout col=lane&15, row=quad*4+r
#pragma unroll
  for (int ni = 0; ni < 4; ++ni) {
    int col = n0 + wc * 64 + ni * 16 + lq;
    float bv = bias[col];
#pragma unroll
    for (int mi = 0; mi < 4; ++mi) {
      int rbase = m0 + wr * 64 + mi * 16 + quad * 4;
#pragma unroll
      for (int r = 0; r < 4; ++r) {
        size_t idxo = (size_t)(rbase + r) * N_DIM + col;
        out[idxo] = acc[mi][ni][r] + bv + residual[idxo];
      }
    }
  }
}

extern "C" void kernel_launch(void* const* d_in, const int* in_sizes, int n_in,
                              void* d_out, int out_size, void* d_ws, size_t ws_size,
                              hipStream_t stream) {
  const float* input    = (const float*)d_in[0];
  const float* residual = (const float*)d_in[1];
  const int*   qweight  = (const int*)d_in[2];
  const float* scales   = (const float*)d_in[3];
  const int*   qzeros   = (const int*)d_in[4];
  const float* bias     = (const float*)d_in[5];
  float* out = (float*)d_out;

  const size_t wt_bytes = (size_t)N_DIM * K_DIM * sizeof(bf16);   // 32 MiB
  const size_t a_bytes  = (size_t)M_DIM * K_DIM * sizeof(bf16);   // 64 MiB

  bf16* wt = (bf16*)d_ws;
  k_dequant<<<64 * 128, 256, 0, stream>>>(qweight, scales, qzeros, wt);

  if (ws_size >= wt_bytes + a_bytes) {
    bf16* a_bf = (bf16*)((char*)d_ws + wt_bytes);
    k_a_convert<<<(M_DIM * K_DIM / 8) / 256, 256, 0, stream>>>(input, a_bf);
    k_gemm<true><<<NBLK_M * NBLK_N, 256, 0, stream>>>(a_bf, wt, bias, residual, out);
  } else {
    k_gemm<false><<<NBLK_M * NBLK_N, 256, 0, stream>>>(input, wt, bias, residual, out);
  }
}